// Round 1
// baseline (892.129 us; speedup 1.0000x reference)
//
#include <hip/hip_runtime.h>

#define NTOK 4096
#define DM   2048
#define DF   4096
#define NEXP 8

typedef __attribute__((ext_vector_type(4))) float f32x4;
typedef __attribute__((ext_vector_type(8))) short s16x8;
typedef __attribute__((ext_vector_type(4))) int   i32x4;

__device__ __forceinline__ unsigned short f2bf(float f) {
  union { float f; unsigned u; } x; x.f = f;
  unsigned r = x.u + 0x7fffu + ((x.u >> 16) & 1u);   // RNE to bf16
  return (unsigned short)(r >> 16);
}

// element (short) offset into a [rows][32] bf16 tile, 16B-chunk XOR swizzle
__device__ __forceinline__ int swz(int row, int ks) {
  return row * 32 + ((ks ^ ((row >> 1) & 3)) << 3);
}

// ---------------- routing ----------------
__global__ void k_zero(int* counts, int* cursor) {
  int i = threadIdx.x;
  if (i < NEXP) { counts[i] = 0; cursor[i] = 0; }
}

__global__ void k_count(const int* __restrict__ idx, int* counts) {
  int t = blockIdx.x * 256 + threadIdx.x;
  if (t >= NTOK) return;
  int e0 = idx[2 * t], e1 = idx[2 * t + 1];
  atomicAdd(&counts[e0], 1);
  if (e1 != e0) atomicAdd(&counts[e1], 1);
}

__global__ void k_scan(const int* __restrict__ counts, int* offsets) {
  if (threadIdx.x == 0) {
    int s = 0;
    for (int e = 0; e < NEXP; e++) { offsets[e] = s; s += counts[e]; }
  }
}

__global__ void k_fill(const int* __restrict__ idx, const float* __restrict__ wts,
                       const int* __restrict__ offsets, int* cursor,
                       int* tokrow, float* wrow, int* rowids) {
  int t = blockIdx.x * 256 + threadIdx.x;
  if (t >= NTOK) return;
  int e0 = idx[2 * t], e1 = idx[2 * t + 1];
  float w0 = wts[2 * t], w1 = wts[2 * t + 1];
  if (e0 == e1) {
    int s = atomicAdd(&cursor[e0], 1);
    int g = offsets[e0] + s;
    tokrow[g] = t; wrow[g] = w0 + w1;
    rowids[2 * t] = g; rowids[2 * t + 1] = -1;
  } else {
    int s0 = atomicAdd(&cursor[e0], 1);
    int g0 = offsets[e0] + s0;
    tokrow[g0] = t; wrow[g0] = w0;
    int s1 = atomicAdd(&cursor[e1], 1);
    int g1 = offsets[e1] + s1;
    tokrow[g1] = t; wrow[g1] = w1;
    rowids[2 * t] = g0; rowids[2 * t + 1] = g1;
  }
}

// ---------------- GEMM1: h = silu(X Wg) * (X Wu), grouped by expert ----------------
__global__ __launch_bounds__(512, 2) void gemm1_kernel(
    const float* __restrict__ X, const float* __restrict__ Wg_all,
    const float* __restrict__ Wu_all, const int* __restrict__ counts,
    const int* __restrict__ offsets, const int* __restrict__ tokrow,
    unsigned short* __restrict__ H) {
  const int e = blockIdx.z;
  const int cnt = counts[e];
  const int m0 = blockIdx.y * 256;
  if (m0 >= cnt) return;
  const int n0 = blockIdx.x * 128;
  const int roff = offsets[e];
  const float* __restrict__ Wg = Wg_all + (size_t)e * DM * DF;
  const float* __restrict__ Wu = Wu_all + (size_t)e * DM * DF;

  __shared__ __attribute__((aligned(16))) short As[2][256 * 32];
  __shared__ __attribute__((aligned(16))) short Bs[2][2][128 * 32];

  const int tid = threadIdx.x;
  // A staging: 2 threads per row, 16 f32 each
  const int ar  = tid >> 1;
  const int aks = (tid & 1) * 2;                 // kslot base
  const int am  = m0 + ar;
  const int atok = (am < cnt) ? tokrow[roff + am] : tokrow[roff];
  const float* __restrict__ xrow = X + (size_t)atok * DM + (tid & 1) * 16;
  // B staging: per-column k-gather (transpose): 256 threads per matrix
  const int bmat  = tid >> 8;                    // 0=Wg 1=Wu
  const int bn    = tid & 127;
  const int bktop = ((tid >> 7) & 1) * 16;
  const float* __restrict__ wcol = (bmat ? Wu : Wg) + n0 + bn;

  const int wave = tid >> 6, lane = tid & 63;
  const int wm = wave >> 1, wn = wave & 1;
  const int lr = lane & 15, ks = lane >> 4;

  f32x4 accg[4][4], accu[4][4];
  #pragma unroll
  for (int i = 0; i < 4; i++)
    #pragma unroll
    for (int j = 0; j < 4; j++) {
      accg[i][j] = f32x4{0.f, 0.f, 0.f, 0.f};
      accu[i][j] = f32x4{0.f, 0.f, 0.f, 0.f};
    }

  auto stage = [&](int b, int k0) {
    const f32x4* ap = (const f32x4*)(xrow + k0);
    f32x4 a0 = ap[0], a1 = ap[1], a2 = ap[2], a3 = ap[3];
    float bv[16];
    const float* p = wcol + (size_t)(k0 + bktop) * DF;
    #pragma unroll
    for (int kk = 0; kk < 16; kk++) { bv[kk] = *p; p += DF; }
    s16x8 s;
    #pragma unroll
    for (int j = 0; j < 4; j++) { s[j] = (short)f2bf(a0[j]); s[4 + j] = (short)f2bf(a1[j]); }
    *(s16x8*)&As[b][swz(ar, aks)] = s;
    #pragma unroll
    for (int j = 0; j < 4; j++) { s[j] = (short)f2bf(a2[j]); s[4 + j] = (short)f2bf(a3[j]); }
    *(s16x8*)&As[b][swz(ar, aks + 1)] = s;
    #pragma unroll
    for (int j = 0; j < 8; j++) s[j] = (short)f2bf(bv[j]);
    *(s16x8*)&Bs[b][bmat][swz(bn, bktop >> 3)] = s;
    #pragma unroll
    for (int j = 0; j < 8; j++) s[j] = (short)f2bf(bv[8 + j]);
    *(s16x8*)&Bs[b][bmat][swz(bn, (bktop >> 3) + 1)] = s;
  };

  stage(0, 0);
  __syncthreads();
  int buf = 0;
  const int nK = DM / 32;
  for (int kt = 0; kt < nK; ++kt) {
    if (kt + 1 < nK) stage(buf ^ 1, (kt + 1) * 32);
    s16x8 af[4], bg[4], bu[4];
    #pragma unroll
    for (int mi = 0; mi < 4; mi++)
      af[mi] = *(const s16x8*)&As[buf][swz(wm * 64 + mi * 16 + lr, ks)];
    #pragma unroll
    for (int ni = 0; ni < 4; ni++) {
      bg[ni] = *(const s16x8*)&Bs[buf][0][swz(wn * 64 + ni * 16 + lr, ks)];
      bu[ni] = *(const s16x8*)&Bs[buf][1][swz(wn * 64 + ni * 16 + lr, ks)];
    }
    #pragma unroll
    for (int mi = 0; mi < 4; mi++)
      #pragma unroll
      for (int ni = 0; ni < 4; ni++) {
        accg[mi][ni] = __builtin_amdgcn_mfma_f32_16x16x32_bf16(af[mi], bg[ni], accg[mi][ni], 0, 0, 0);
        accu[mi][ni] = __builtin_amdgcn_mfma_f32_16x16x32_bf16(af[mi], bu[ni], accu[mi][ni], 0, 0, 0);
      }
    __syncthreads();
    buf ^= 1;
  }

  #pragma unroll
  for (int mi = 0; mi < 4; mi++) {
    #pragma unroll
    for (int r = 0; r < 4; r++) {
      int row = wm * 64 + mi * 16 + ks * 4 + r;
      if (m0 + row < cnt) {
        unsigned short* hrow = H + (size_t)(roff + m0 + row) * DF + n0 + wn * 64 + lr;
        #pragma unroll
        for (int ni = 0; ni < 4; ni++) {
          float g = accg[mi][ni][r], u = accu[mi][ni][r];
          float sv = g / (1.f + __expf(-g));
          hrow[ni * 16] = f2bf(sv * u);
        }
      }
    }
  }
}

// ---------------- GEMM2: out_pairs = (h Wd) * w_row ----------------
__global__ __launch_bounds__(512, 2) void gemm2_kernel(
    const unsigned short* __restrict__ H, const float* __restrict__ Wd_all,
    const int* __restrict__ counts, const int* __restrict__ offsets,
    const float* __restrict__ wrow, float* __restrict__ OP) {
  const int e = blockIdx.z;
  const int cnt = counts[e];
  const int m0 = blockIdx.y * 256;
  if (m0 >= cnt) return;
  const int n0 = blockIdx.x * 128;
  const int roff = offsets[e];
  const float* __restrict__ Wd = Wd_all + (size_t)e * DF * DM;

  __shared__ __attribute__((aligned(16))) short As[2][256 * 32];
  __shared__ __attribute__((aligned(16))) short Bs[2][128 * 32];
  __shared__ float wl[256];

  const int tid = threadIdx.x;
  if (tid < 256) wl[tid] = (m0 + tid < cnt) ? wrow[roff + m0 + tid] : 0.f;

  const int ar  = tid >> 1;
  const int aks = (tid & 1) * 2;
  const int am  = m0 + ar;
  const int arow = (am < cnt) ? (roff + am) : roff;
  const unsigned short* __restrict__ hrow = H + (size_t)arow * DF + (tid & 1) * 16;

  const int bn  = tid & 127;
  const int bkg = tid >> 7;                      // 0..3
  const float* __restrict__ wcol = Wd + n0 + bn;

  const int wave = tid >> 6, lane = tid & 63;
  const int wm = wave >> 1, wn = wave & 1;
  const int lr = lane & 15, ks = lane >> 4;

  f32x4 acc[4][4];
  #pragma unroll
  for (int i = 0; i < 4; i++)
    #pragma unroll
    for (int j = 0; j < 4; j++) acc[i][j] = f32x4{0.f, 0.f, 0.f, 0.f};

  auto stage = [&](int b, int k0) {
    const i32x4* ap = (const i32x4*)(hrow + k0);
    i32x4 h0 = ap[0], h1 = ap[1];
    float bv[8];
    const float* p = wcol + (size_t)(k0 + bkg * 8) * DM;
    #pragma unroll
    for (int kk = 0; kk < 8; kk++) { bv[kk] = *p; p += DM; }
    *(i32x4*)&As[b][swz(ar, aks)] = h0;
    *(i32x4*)&As[b][swz(ar, aks + 1)] = h1;
    s16x8 s;
    #pragma unroll
    for (int j = 0; j < 8; j++) s[j] = (short)f2bf(bv[j]);
    *(s16x8*)&Bs[b][swz(bn, bkg)] = s;
  };

  stage(0, 0);
  __syncthreads();
  int buf = 0;
  const int nK = DF / 32;
  for (int kt = 0; kt < nK; ++kt) {
    if (kt + 1 < nK) stage(buf ^ 1, (kt + 1) * 32);
    s16x8 af[4], bf_[4];
    #pragma unroll
    for (int mi = 0; mi < 4; mi++)
      af[mi] = *(const s16x8*)&As[buf][swz(wm * 64 + mi * 16 + lr, ks)];
    #pragma unroll
    for (int ni = 0; ni < 4; ni++)
      bf_[ni] = *(const s16x8*)&Bs[buf][swz(wn * 64 + ni * 16 + lr, ks)];
    #pragma unroll
    for (int mi = 0; mi < 4; mi++)
      #pragma unroll
      for (int ni = 0; ni < 4; ni++)
        acc[mi][ni] = __builtin_amdgcn_mfma_f32_16x16x32_bf16(af[mi], bf_[ni], acc[mi][ni], 0, 0, 0);
    __syncthreads();
    buf ^= 1;
  }

  #pragma unroll
  for (int mi = 0; mi < 4; mi++) {
    #pragma unroll
    for (int r = 0; r < 4; r++) {
      int row = wm * 64 + mi * 16 + ks * 4 + r;
      if (m0 + row < cnt) {
        float wgt = wl[row];
        float* orow = OP + (size_t)(roff + m0 + row) * DM + n0 + wn * 64 + lr;
        #pragma unroll
        for (int ni = 0; ni < 4; ni++) orow[ni * 16] = acc[mi][ni][r] * wgt;
      }
    }
  }
}

// ---------------- combine: out[t] = sum of the token's (<=2) weighted rows ----------------
__global__ void k_combine(const float* __restrict__ OP, const int* __restrict__ rowids,
                          float* __restrict__ out) {
  int gid = blockIdx.x * 256 + threadIdx.x;
  if (gid >= NTOK * DM / 4) return;
  int t = gid >> 9;
  int c = (gid & 511) << 2;
  int r0 = rowids[2 * t], r1 = rowids[2 * t + 1];
  f32x4 v = *(const f32x4*)(OP + (size_t)r0 * DM + c);
  if (r1 >= 0) {
    f32x4 v1 = *(const f32x4*)(OP + (size_t)r1 * DM + c);
    v = v + v1;
  }
  *(f32x4*)(out + (size_t)t * DM + c) = v;
}

extern "C" void kernel_launch(void* const* d_in, const int* in_sizes, int n_in,
                              void* d_out, int out_size, void* d_ws, size_t ws_size,
                              hipStream_t stream) {
  (void)in_sizes; (void)n_in; (void)out_size; (void)ws_size;
  const float* X   = (const float*)d_in[0];
  const int*   idx = (const int*)d_in[1];
  const float* wts = (const float*)d_in[2];
  const float* Wg  = (const float*)d_in[3];
  const float* Wu  = (const float*)d_in[4];
  const float* Wd  = (const float*)d_in[5];
  float* out = (float*)d_out;

  uint8_t* w = (uint8_t*)d_ws;
  int*   counts  = (int*)(w + 0);
  int*   cursor  = (int*)(w + 64);
  int*   offsets = (int*)(w + 128);
  int*   tokrow  = (int*)(w + 256);
  float* wrow    = (float*)(w + 256 + 4 * 8192);
  int*   rowids  = (int*)(w + 256 + 8 * 8192);
  unsigned short* H = (unsigned short*)(w + 131072);
  float* OP = (float*)(w + 131072 + (size_t)8192 * DF * 2);

  k_zero<<<1, 64, 0, stream>>>(counts, cursor);
  k_count<<<16, 256, 0, stream>>>(idx, counts);
  k_scan<<<1, 64, 0, stream>>>(counts, offsets);
  k_fill<<<16, 256, 0, stream>>>(idx, wts, offsets, cursor, tokrow, wrow, rowids);
  gemm1_kernel<<<dim3(DF / 128, 16, NEXP), 512, 0, stream>>>(X, Wg, Wu, counts, offsets, tokrow, H);
  gemm2_kernel<<<dim3(DM / 128, 16, NEXP), 512, 0, stream>>>(H, Wd, counts, offsets, wrow, OP);
  k_combine<<<(NTOK * DM / 4) / 256, 256, 0, stream>>>(OP, rowids, out);
}

// Round 2
// 889.225 us; speedup vs baseline: 1.0033x; 1.0033x over previous
//
#include <hip/hip_runtime.h>
#include <hip/hip_bf16.h>

#define NTOK 4096
#define DM   2048
#define DF   4096
#define NEXP 8

typedef __attribute__((ext_vector_type(4))) float f32x4;
typedef __attribute__((ext_vector_type(8))) short s16x8;
typedef __attribute__((ext_vector_type(4))) int   i32x4;

__device__ __forceinline__ unsigned short f2bf(float f) {
  union { float f; unsigned u; } x; x.f = f;
  unsigned r = x.u + 0x7fffu + ((x.u >> 16) & 1u);   // RNE to bf16
  return (unsigned short)(r >> 16);
}

__device__ __forceinline__ unsigned pack2(float lo, float hi) {
  __hip_bfloat162 h2 = __float22bfloat162_rn(make_float2(lo, hi));
  return *reinterpret_cast<unsigned*>(&h2);
}

// element (short) offset into a [rows][32] bf16 tile, 16B-chunk XOR swizzle
__device__ __forceinline__ int swz(int row, int ks) {
  return row * 32 + ((ks ^ ((row >> 1) & 3)) << 3);
}

// ---------------- routing ----------------
__global__ void k_zero(int* counts, int* cursor) {
  int i = threadIdx.x;
  if (i < NEXP) { counts[i] = 0; cursor[i] = 0; }
}

__global__ void k_count(const int* __restrict__ idx, int* counts) {
  int t = blockIdx.x * 256 + threadIdx.x;
  if (t >= NTOK) return;
  int e0 = idx[2 * t], e1 = idx[2 * t + 1];
  atomicAdd(&counts[e0], 1);
  if (e1 != e0) atomicAdd(&counts[e1], 1);
}

__global__ void k_scan(const int* __restrict__ counts, int* offsets) {
  if (threadIdx.x == 0) {
    int s = 0;
    for (int e = 0; e < NEXP; e++) { offsets[e] = s; s += counts[e]; }
  }
}

__global__ void k_fill(const int* __restrict__ idx, const float* __restrict__ wts,
                       const int* __restrict__ offsets, int* cursor,
                       int* tokrow, float* wrow, int* rowids) {
  int t = blockIdx.x * 256 + threadIdx.x;
  if (t >= NTOK) return;
  int e0 = idx[2 * t], e1 = idx[2 * t + 1];
  float w0 = wts[2 * t], w1 = wts[2 * t + 1];
  if (e0 == e1) {
    int s = atomicAdd(&cursor[e0], 1);
    int g = offsets[e0] + s;
    tokrow[g] = t; wrow[g] = w0 + w1;
    rowids[2 * t] = g; rowids[2 * t + 1] = -1;
  } else {
    int s0 = atomicAdd(&cursor[e0], 1);
    int g0 = offsets[e0] + s0;
    tokrow[g0] = t; wrow[g0] = w0;
    int s1 = atomicAdd(&cursor[e1], 1);
    int g1 = offsets[e1] + s1;
    tokrow[g1] = t; wrow[g1] = w1;
    rowids[2 * t] = g0; rowids[2 * t + 1] = g1;
  }
}

// ---------------- GEMM1: h = silu(X Wg) * (X Wu), grouped by expert ----------------
__global__ __launch_bounds__(512, 2) void gemm1_kernel(
    const float* __restrict__ X, const float* __restrict__ Wg_all,
    const float* __restrict__ Wu_all, const int* __restrict__ counts,
    const int* __restrict__ offsets, const int* __restrict__ tokrow,
    unsigned short* __restrict__ H) {
  const int e = blockIdx.z;
  const int cnt = counts[e];
  const int m0 = blockIdx.y * 256;
  if (m0 >= cnt) return;
  const int n0 = blockIdx.x * 128;
  const int roff = offsets[e];

  __shared__ __attribute__((aligned(16))) short As[2][256 * 32];
  __shared__ __attribute__((aligned(16))) short Bs[2][2][128 * 32];

  const int tid = threadIdx.x;
  // A staging: 2 threads per row, 16 f32 each
  const int ar  = tid >> 1;
  const int aks = (tid & 1) * 2;                 // kslot base
  const int am  = m0 + ar;
  const int atok = (am < cnt) ? tokrow[roff + am] : tokrow[roff];
  const float* __restrict__ xrow = X + (size_t)atok * DM + (tid & 1) * 16;
  // B staging: per-column k-gather (transpose): 256 threads per matrix
  const int bmat  = tid >> 8;                    // 0=Wg 1=Wu
  const int bn    = tid & 127;
  const int bktop = ((tid >> 7) & 1) * 16;
  const float* __restrict__ wcol =
      (bmat ? Wu_all : Wg_all) + (size_t)e * DM * DF + n0 + bn;

  const int wave = tid >> 6, lane = tid & 63;
  const int wm = wave >> 1, wn = wave & 1;
  const int lr = lane & 15, ks = lane >> 4;

  f32x4 accg[4][4], accu[4][4];
  #pragma unroll
  for (int i = 0; i < 4; i++)
    #pragma unroll
    for (int j = 0; j < 4; j++) {
      accg[i][j] = f32x4{0.f, 0.f, 0.f, 0.f};
      accu[i][j] = f32x4{0.f, 0.f, 0.f, 0.f};
    }

  float aR[16], bR[16];

  auto loadA = [&](int k0) {
    const f32x4* ap = (const f32x4*)(xrow + k0);
    *(f32x4*)&aR[0]  = ap[0];
    *(f32x4*)&aR[4]  = ap[1];
    *(f32x4*)&aR[8]  = ap[2];
    *(f32x4*)&aR[12] = ap[3];
  };
  auto loadB = [&](int k0) {
    const float* p = wcol + (size_t)(k0 + bktop) * DF;
    #pragma unroll
    for (int kk = 0; kk < 16; kk++) { bR[kk] = *p; p += DF; }
  };
  auto writeAB = [&](int b) {
    union { s16x8 s; unsigned u[4]; } q;
    #pragma unroll
    for (int j = 0; j < 4; j++) q.u[j] = pack2(aR[2 * j], aR[2 * j + 1]);
    *(s16x8*)&As[b][swz(ar, aks)] = q.s;
    #pragma unroll
    for (int j = 0; j < 4; j++) q.u[j] = pack2(aR[8 + 2 * j], aR[9 + 2 * j]);
    *(s16x8*)&As[b][swz(ar, aks + 1)] = q.s;
    #pragma unroll
    for (int j = 0; j < 4; j++) q.u[j] = pack2(bR[2 * j], bR[2 * j + 1]);
    *(s16x8*)&Bs[b][bmat][swz(bn, bktop >> 3)] = q.s;
    #pragma unroll
    for (int j = 0; j < 4; j++) q.u[j] = pack2(bR[8 + 2 * j], bR[9 + 2 * j]);
    *(s16x8*)&Bs[b][bmat][swz(bn, (bktop >> 3) + 1)] = q.s;
  };

  loadA(0); loadB(0);
  writeAB(0);
  __syncthreads();
  int buf = 0;
  const int nK = DM / 32;
  for (int kt = 0; kt < nK; ++kt) {
    const bool more = (kt + 1 < nK);
    if (more) { loadA((kt + 1) * 32); loadB((kt + 1) * 32); }  // issue early
    s16x8 af[4], bg[4], bu[4];
    #pragma unroll
    for (int mi = 0; mi < 4; mi++)
      af[mi] = *(const s16x8*)&As[buf][swz(wm * 64 + mi * 16 + lr, ks)];
    #pragma unroll
    for (int ni = 0; ni < 4; ni++) {
      bg[ni] = *(const s16x8*)&Bs[buf][0][swz(wn * 64 + ni * 16 + lr, ks)];
      bu[ni] = *(const s16x8*)&Bs[buf][1][swz(wn * 64 + ni * 16 + lr, ks)];
    }
    #pragma unroll
    for (int mi = 0; mi < 4; mi++)
      #pragma unroll
      for (int ni = 0; ni < 4; ni++) {
        accg[mi][ni] = __builtin_amdgcn_mfma_f32_16x16x32_bf16(af[mi], bg[ni], accg[mi][ni], 0, 0, 0);
        accu[mi][ni] = __builtin_amdgcn_mfma_f32_16x16x32_bf16(af[mi], bu[ni], accu[mi][ni], 0, 0, 0);
      }
    if (more) writeAB(buf ^ 1);   // convert + ds_write late (loads have drained under MFMA)
    __syncthreads();
    buf ^= 1;
  }

  #pragma unroll
  for (int mi = 0; mi < 4; mi++) {
    #pragma unroll
    for (int r = 0; r < 4; r++) {
      int row = wm * 64 + mi * 16 + ks * 4 + r;
      if (m0 + row < cnt) {
        unsigned short* hrow = H + (size_t)(roff + m0 + row) * DF + n0 + wn * 64 + lr;
        #pragma unroll
        for (int ni = 0; ni < 4; ni++) {
          float g = accg[mi][ni][r], u = accu[mi][ni][r];
          float sv = g / (1.f + __expf(-g));
          hrow[ni * 16] = f2bf(sv * u);
        }
      }
    }
  }
}

// ---------------- GEMM2: out_pairs = (h Wd) * w_row ----------------
__global__ __launch_bounds__(512, 2) void gemm2_kernel(
    const unsigned short* __restrict__ H, const float* __restrict__ Wd_all,
    const int* __restrict__ counts, const int* __restrict__ offsets,
    const float* __restrict__ wrow, float* __restrict__ OP) {
  const int e = blockIdx.z;
  const int cnt = counts[e];
  const int m0 = blockIdx.y * 256;
  if (m0 >= cnt) return;
  const int n0 = blockIdx.x * 128;
  const int roff = offsets[e];
  const float* __restrict__ Wd = Wd_all + (size_t)e * DF * DM;

  __shared__ __attribute__((aligned(16))) short As[2][256 * 32];
  __shared__ __attribute__((aligned(16))) short Bs[2][128 * 32];
  __shared__ float wl[256];

  const int tid = threadIdx.x;
  if (tid < 256) wl[tid] = (m0 + tid < cnt) ? wrow[roff + m0 + tid] : 0.f;

  const int ar  = tid >> 1;
  const int aks = (tid & 1) * 2;
  const int am  = m0 + ar;
  const int arow = (am < cnt) ? (roff + am) : roff;
  const unsigned short* __restrict__ hrow = H + (size_t)arow * DF + (tid & 1) * 16;

  const int bn  = tid & 127;
  const int bkg = tid >> 7;                      // 0..3
  const float* __restrict__ wcol = Wd + n0 + bn;

  const int wave = tid >> 6, lane = tid & 63;
  const int wm = wave >> 1, wn = wave & 1;
  const int lr = lane & 15, ks = lane >> 4;

  f32x4 acc[4][4];
  #pragma unroll
  for (int i = 0; i < 4; i++)
    #pragma unroll
    for (int j = 0; j < 4; j++) acc[i][j] = f32x4{0.f, 0.f, 0.f, 0.f};

  i32x4 h0, h1;
  float bR[8];

  auto loadA = [&](int k0) {
    const i32x4* ap = (const i32x4*)(hrow + k0);
    h0 = ap[0]; h1 = ap[1];
  };
  auto loadB = [&](int k0) {
    const float* p = wcol + (size_t)(k0 + bkg * 8) * DM;
    #pragma unroll
    for (int kk = 0; kk < 8; kk++) { bR[kk] = *p; p += DM; }
  };
  auto writeAB = [&](int b) {
    *(i32x4*)&As[b][swz(ar, aks)]     = h0;
    *(i32x4*)&As[b][swz(ar, aks + 1)] = h1;
    union { s16x8 s; unsigned u[4]; } q;
    #pragma unroll
    for (int j = 0; j < 4; j++) q.u[j] = pack2(bR[2 * j], bR[2 * j + 1]);
    *(s16x8*)&Bs[b][swz(bn, bkg)] = q.s;
  };

  loadA(0); loadB(0);
  writeAB(0);
  __syncthreads();
  int buf = 0;
  const int nK = DF / 32;
  for (int kt = 0; kt < nK; ++kt) {
    const bool more = (kt + 1 < nK);
    if (more) { loadA((kt + 1) * 32); loadB((kt + 1) * 32); }
    s16x8 af[4], bf_[4];
    #pragma unroll
    for (int mi = 0; mi < 4; mi++)
      af[mi] = *(const s16x8*)&As[buf][swz(wm * 64 + mi * 16 + lr, ks)];
    #pragma unroll
    for (int ni = 0; ni < 4; ni++)
      bf_[ni] = *(const s16x8*)&Bs[buf][swz(wn * 64 + ni * 16 + lr, ks)];
    #pragma unroll
    for (int mi = 0; mi < 4; mi++)
      #pragma unroll
      for (int ni = 0; ni < 4; ni++)
        acc[mi][ni] = __builtin_amdgcn_mfma_f32_16x16x32_bf16(af[mi], bf_[ni], acc[mi][ni], 0, 0, 0);
    if (more) writeAB(buf ^ 1);
    __syncthreads();
    buf ^= 1;
  }

  #pragma unroll
  for (int mi = 0; mi < 4; mi++) {
    #pragma unroll
    for (int r = 0; r < 4; r++) {
      int row = wm * 64 + mi * 16 + ks * 4 + r;
      if (m0 + row < cnt) {
        float wgt = wl[row];
        float* orow = OP + (size_t)(roff + m0 + row) * DM + n0 + wn * 64 + lr;
        #pragma unroll
        for (int ni = 0; ni < 4; ni++) orow[ni * 16] = acc[mi][ni][r] * wgt;
      }
    }
  }
}

// ---------------- combine: out[t] = sum of the token's (<=2) weighted rows ----------------
__global__ void k_combine(const float* __restrict__ OP, const int* __restrict__ rowids,
                          float* __restrict__ out) {
  int gid = blockIdx.x * 256 + threadIdx.x;
  if (gid >= NTOK * DM / 4) return;
  int t = gid >> 9;
  int c = (gid & 511) << 2;
  int r0 = rowids[2 * t], r1 = rowids[2 * t + 1];
  f32x4 v = *(const f32x4*)(OP + (size_t)r0 * DM + c);
  if (r1 >= 0) {
    f32x4 v1 = *(const f32x4*)(OP + (size_t)r1 * DM + c);
    v = v + v1;
  }
  *(f32x4*)(out + (size_t)t * DM + c) = v;
}

extern "C" void kernel_launch(void* const* d_in, const int* in_sizes, int n_in,
                              void* d_out, int out_size, void* d_ws, size_t ws_size,
                              hipStream_t stream) {
  (void)in_sizes; (void)n_in; (void)out_size; (void)ws_size;
  const float* X   = (const float*)d_in[0];
  const int*   idx = (const int*)d_in[1];
  const float* wts = (const float*)d_in[2];
  const float* Wg  = (const float*)d_in[3];
  const float* Wu  = (const float*)d_in[4];
  const float* Wd  = (const float*)d_in[5];
  float* out = (float*)d_out;

  uint8_t* w = (uint8_t*)d_ws;
  int*   counts  = (int*)(w + 0);
  int*   cursor  = (int*)(w + 64);
  int*   offsets = (int*)(w + 128);
  int*   tokrow  = (int*)(w + 256);
  float* wrow    = (float*)(w + 256 + 4 * 8192);
  int*   rowids  = (int*)(w + 256 + 8 * 8192);
  unsigned short* H = (unsigned short*)(w + 131072);
  float* OP = (float*)(w + 131072 + (size_t)8192 * DF * 2);

  k_zero<<<1, 64, 0, stream>>>(counts, cursor);
  k_count<<<16, 256, 0, stream>>>(idx, counts);
  k_scan<<<1, 64, 0, stream>>>(counts, offsets);
  k_fill<<<16, 256, 0, stream>>>(idx, wts, offsets, cursor, tokrow, wrow, rowids);
  gemm1_kernel<<<dim3(DF / 128, 16, NEXP), 512, 0, stream>>>(X, Wg, Wu, counts, offsets, tokrow, H);
  gemm2_kernel<<<dim3(DM / 128, 16, NEXP), 512, 0, stream>>>(H, Wd, counts, offsets, wrow, OP);
  k_combine<<<(NTOK * DM / 4) / 256, 256, 0, stream>>>(OP, rowids, out);
}